// Round 8
// baseline (3249.496 us; speedup 1.0000x reference)
//
#include <hip/hip_runtime.h>
#include <hip/hip_bf16.h>

typedef __bf16 bf16x8 __attribute__((ext_vector_type(8)));
typedef float  f32x4  __attribute__((ext_vector_type(4)));

#define MFMA_BF16(a, b, c) __builtin_amdgcn_mfma_f32_16x16x32_bf16((a), (b), (c), 0, 0, 0)

constexpr int TT = 160, BB = 2048, HH = 512, EE = 64, VV = 128, G3 = 1536;
constexpr size_t LPROB_ELEMS = (size_t)TT * BB * VV;  // 41,943,040

// phase-1 LDS: Whh tile [3 gates][16 rows][1024B + 16B pad]
constexpr int BSTRIDE = 1040;               // 1024 + 16 pad -> 2-way banks (free)
constexpr int GSZ = 16 * BSTRIDE;           // 16,640 B per gate
constexpr int SMEM_BYTES = 3 * GSZ;         // 49,920 B

__device__ __forceinline__ float fsigmoid(float x) {
  return 1.0f / (1.0f + __expf(-x));
}
__device__ __forceinline__ float ftanh(float x) {
  float ax = fabsf(x);
  float e = __expf(-2.0f * ax);
  float r = (1.0f - e) / (1.0f + e);
  return x < 0.0f ? -r : r;
}
// dual-dtype scalar load: isbf ? bf16[i] : f32[i]
__device__ __forceinline__ float ld(const void* p, long i, int isbf) {
  return isbf ? (float)((const __bf16*)p)[i] : ((const float*)p)[i];
}

// ---------------- dtype probe ----------------
__global__ __launch_bounds__(256) void probe_dtype(
    const unsigned short* __restrict__ eh, int* __restrict__ flagp) {
  __shared__ int sb[256];
  int tid = threadIdx.x;
  int cnt = 0;
  for (int i = tid; i < 4096; i += 256) {
    unsigned short u = eh[i];
    int e = (u >> 7) & 0xFF;
    if ((u & 0x7FFF) == 0 || (e >= 90 && e <= 150)) cnt++;
  }
  sb[tid] = cnt;
  __syncthreads();
  for (int s = 128; s > 0; s >>= 1) {
    if (tid < s) sb[tid] += sb[tid + s];
    __syncthreads();
  }
  if (tid == 0) *flagp = (sb[0] > 3072) ? 1 : 0;
}

// ---------------- prep kernels ----------------
__global__ __launch_bounds__(256) void conv_w(
    const void* __restrict__ Whh, const void* __restrict__ Wout,
    const void* __restrict__ bhh, const void* __restrict__ bout,
    const int* __restrict__ flagp,
    __bf16* __restrict__ Whh_b, __bf16* __restrict__ Wout_b,
    float* __restrict__ bhhn_f, float* __restrict__ bout_f) {
  const int isbf = *flagp;
  int idx = blockIdx.x * 256 + threadIdx.x;   // 3072 blocks -> 786,432 = 1536*512
  Whh_b[idx] = (__bf16)ld(Whh, idx, isbf);
  if (idx < VV * HH) Wout_b[idx] = (__bf16)ld(Wout, idx, isbf);
  if (idx < HH) bhhn_f[idx] = ld(bhh, 2 * HH + idx, isbf);
  if (idx < VV) bout_f[idx] = ld(bout, idx, isbf);
}

// gi_vocab[v][n] = relu(emb[v]) . W_ih[n] + b_ih[n] + (n < 1024 ? b_hh[n] : 0)
__global__ __launch_bounds__(256) void prep_gi(
    const void* __restrict__ emb, const void* __restrict__ Wih,
    const void* __restrict__ bih, const void* __restrict__ bhh,
    const int* __restrict__ flagp, float* __restrict__ gi) {
  const int isbf = *flagp;
  int idx = blockIdx.x * 256 + threadIdx.x;   // 768 blocks -> exactly 128*1536
  int v = idx / G3;
  int n = idx - v * G3;
  float s = 0.0f;
#pragma unroll 8
  for (int k = 0; k < EE; ++k) {
    float x = ld(emb, v * EE + k, isbf);
    x = x > 0.0f ? x : 0.0f;
    s += x * ld(Wih, (long)n * EE + k, isbf);
  }
  s += ld(bih, n, isbf);
  if (n < 2 * HH) s += ld(bhh, n, isbf);
  gi[idx] = s;
}

// h0 = encoder_hidden[0]: fp32 state + bf16 mirror for MFMA
__global__ __launch_bounds__(256) void prep_h0(
    const void* __restrict__ ehid, const int* __restrict__ flagp,
    float* __restrict__ hf, __bf16* __restrict__ hb0) {
  const int isbf = *flagp;
  int idx = blockIdx.x * 256 + threadIdx.x;   // 4096 blocks -> 1,048,576
  float v = ld(ehid, idx, isbf);
  hf[idx] = v;
  hb0[idx] = (__bf16)v;
}

// ---------------- per-step kernel ----------------
// Grid 640 x 256, launched 161 times. Kernel boundary = device-wide sync.
// Blocks [0,512): phase 1 — grp=bid&15 owns rows grp*128..+128; colTile=bid>>4
//   owns output cols colTile*16..+16 of all 3 gates. B tile (49KB) LDS-staged
//   (all 4 waves consume the SAME tile -> 4x dedup). tgt issued first (longest
//   dependent chain), epilogue inputs prefetched before the K-loop.
//   t==159: final hidden written directly from registers; t==160: return.
// Blocks [512,640): phase 2 — logits + log_softmax of h(t-1), 16 rows each.
//   B read DIRECT from global (waves read disjoint Wout rows -> LDS staging
//   has no dedup value; L2 serves the 16 same-XCD blocks). Zero barriers
//   until softmax staging.
__global__ __launch_bounds__(256, 3) void gru_step(
    const __bf16* __restrict__ Whh, const __bf16* __restrict__ Wout,
    const float* __restrict__ bhhn_f, const float* __restrict__ bout_f,
    const float* __restrict__ gi, const int* __restrict__ tgt,
    const int* __restrict__ flagp,
    const __bf16* __restrict__ hbs,   // h(t-1) bf16
    __bf16* __restrict__ hbd,         // h(t) bf16 (written)
    float* __restrict__ hf,           // h f32, single buffer (own-element RMW)
    void* __restrict__ outp, int t) {
  __shared__ __align__(16) char smem[SMEM_BYTES];

  const int tid = threadIdx.x;
  const int bid = blockIdx.x;
  const int w = tid >> 6;
  const int lane = tid & 63;
  const int q = lane >> 4;
  const int l16 = lane & 15;
  const int isbf = *flagp;
  const f32x4 fzero = {0.0f, 0.0f, 0.0f, 0.0f};

  if (bid < 512) {
    if (t == 160) return;   // final hidden already written at t==159
    const int grp = bid & 15;
    const int colTile = bid >> 4;
    const int mBase = grp * 128 + w * 32;
    const int c = colTile * 16 + l16;
    const float bhhn = bhhn_f[c];

    // ---- tgt first: head of the longest dependent chain (tgt -> gi) ----
    int tk[2][4];
#pragma unroll
    for (int ms = 0; ms < 2; ++ms)
#pragma unroll
      for (int rg = 0; rg < 4; ++rg) {
        int row = mBase + ms * 16 + q * 4 + rg;
        tk[ms][rg] = (t == 0) ? 0 : tgt[row * TT + (t - 1)];
      }

    // ---- stage B tile: Whh rows {g*512 + colTile*16 .. +16}, 49KB burst ----
    {
      const char* src0 = (const char*)(Whh + (size_t)(colTile * 16) * HH);
#pragma unroll
      for (int g = 0; g < 3; ++g) {
        const char* sg = src0 + (size_t)g * (HH * HH * 2);
#pragma unroll
        for (int j = 0; j < 4; ++j) {
          int off = (tid + j * 256) * 16;        // 0..16368
          bf16x8 v = *(const bf16x8*)(sg + off);
          *(bf16x8*)(smem + g * GSZ + (off >> 10) * BSTRIDE + (off & 1023)) = v;
        }
      }
    }

    // ---- prefetch remaining epilogue inputs ----
    float hold[2][4];
#pragma unroll
    for (int ms = 0; ms < 2; ++ms)
#pragma unroll
      for (int rg = 0; rg < 4; ++rg) {
        int row = mBase + ms * 16 + q * 4 + rg;
        hold[ms][rg] = hf[(size_t)row * HH + c];
      }
    float gv[2][4][3];
#pragma unroll
    for (int ms = 0; ms < 2; ++ms)
#pragma unroll
      for (int rg = 0; rg < 4; ++rg) {
        const float* gvp = gi + (size_t)tk[ms][rg] * G3 + c;
        gv[ms][rg][0] = gvp[0];
        gv[ms][rg][1] = gvp[HH];
        gv[ms][rg][2] = gvp[2 * HH];
      }
    __syncthreads();   // B tile staged

    // ---- gh = h(t-1) @ W_hh^T : A from global, B from LDS ----
    f32x4 acc[2][3];
#pragma unroll
    for (int ms = 0; ms < 2; ++ms)
#pragma unroll
      for (int gg = 0; gg < 3; ++gg) acc[ms][gg] = fzero;

    const __bf16* aRow0 = hbs + (size_t)(mBase + l16) * HH + q * 8;
    const __bf16* aRow1 = aRow0 + 16 * HH;
    const char* bb = smem + l16 * BSTRIDE + q * 16;

#pragma unroll 8
    for (int k0 = 0; k0 < HH; k0 += 32) {
      bf16x8 a0 = *(const bf16x8*)(aRow0 + k0);
      bf16x8 a1 = *(const bf16x8*)(aRow1 + k0);
#pragma unroll
      for (int gg = 0; gg < 3; ++gg) {
        bf16x8 bf = *(const bf16x8*)(bb + gg * GSZ + k0 * 2);
        acc[0][gg] = MFMA_BF16(a0, bf, acc[0][gg]);
        acc[1][gg] = MFMA_BF16(a1, bf, acc[1][gg]);
      }
    }

    // ---- GRU epilogue: everything already in registers ----
#pragma unroll
    for (int ms = 0; ms < 2; ++ms) {
#pragma unroll
      for (int rg = 0; rg < 4; ++rg) {
        int row = mBase + ms * 16 + q * 4 + rg;
        float r_ = fsigmoid(acc[ms][0][rg] + gv[ms][rg][0]);
        float z_ = fsigmoid(acc[ms][1][rg] + gv[ms][rg][1]);
        float n_ = ftanh(gv[ms][rg][2] + r_ * (acc[ms][2][rg] + bhhn));
        size_t hi = (size_t)row * HH + c;
        float hv = (1.0f - z_) * n_ + z_ * hold[ms][rg];
        hf[hi] = hv;
        hbd[hi] = (__bf16)hv;
        if (t == 159) {   // final hidden straight from the register value
          size_t o = LPROB_ELEMS + hi;
          if (isbf) ((__bf16*)outp)[o] = (__bf16)hv;
          else      ((float*)outp)[o] = hv;
        }
      }
    }
  } else {
    // ---- phase 2: logits + log_softmax of h(t-1), direct-B K-loop ----
    if (t == 0) return;
    const int rb = (bid - 512) * 16;
    const __bf16* aR  = hbs + (size_t)(rb + l16) * HH + q * 8;
    const __bf16* bR0 = Wout + (size_t)(w * 32 + l16) * HH + q * 8;
    const __bf16* bR1 = bR0 + 16 * HH;
    float* llds = (float*)smem;

    f32x4 acc2[2];
    acc2[0] = fzero; acc2[1] = fzero;
#pragma unroll
    for (int k0 = 0; k0 < HH; k0 += 32) {
      bf16x8 a  = *(const bf16x8*)(aR + k0);
      bf16x8 b0 = *(const bf16x8*)(bR0 + k0);
      bf16x8 b1 = *(const bf16x8*)(bR1 + k0);
      acc2[0] = MFMA_BF16(a, b0, acc2[0]);
      acc2[1] = MFMA_BF16(a, b1, acc2[1]);
    }

#pragma unroll
    for (int j = 0; j < 2; ++j) {
      int col = (w * 2 + j) * 16 + l16;
      float bo = bout_f[col];
#pragma unroll
      for (int rg = 0; rg < 4; ++rg)
        llds[(q * 4 + rg) * 132 + col] = acc2[j][rg] + bo;
    }
    __syncthreads();
    {
      int row = tid >> 4, seg = tid & 15;
      const float* lr = &llds[row * 132 + seg * 8];
      float x[8];
      float m = -3.0e38f;
#pragma unroll
      for (int i = 0; i < 8; ++i) { x[i] = lr[i]; m = fmaxf(m, x[i]); }
#pragma unroll
      for (int d = 1; d < 16; d <<= 1) m = fmaxf(m, __shfl_xor(m, d, 16));
      float s = 0.0f;
#pragma unroll
      for (int i = 0; i < 8; ++i) s += __expf(x[i] - m);
#pragma unroll
      for (int d = 1; d < 16; d <<= 1) s += __shfl_xor(s, d, 16);
      float lg = m + __logf(s);
      size_t ofs = (size_t)(t - 1) * (BB * VV) + (size_t)(rb + row) * VV + seg * 8;
      if (isbf) {
        bf16x8 ov;
#pragma unroll
        for (int i = 0; i < 8; ++i) ov[i] = (__bf16)(x[i] - lg);
        *(bf16x8*)((__bf16*)outp + ofs) = ov;
      } else {
        f32x4 o0, o1;
#pragma unroll
        for (int i = 0; i < 4; ++i) { o0[i] = x[i] - lg; o1[i] = x[4 + i] - lg; }
        float* dst = (float*)outp + ofs;
        *(f32x4*)dst = o0;
        *(f32x4*)(dst + 4) = o1;
      }
    }
  }
}

// ---------------- launcher ----------------
extern "C" void kernel_launch(void* const* d_in, const int* in_sizes, int n_in,
                              void* d_out, int out_size, void* d_ws, size_t ws_size,
                              hipStream_t stream) {
  // setup_inputs order:
  // 0 encoder_outputs (unused), 1 encoder_hidden, 2 target_tensor, 3 embedding,
  // 4 W_ih, 5 W_hh, 6 b_ih, 7 b_hh, 8 W_out, 9 b_out
  const void* ehid = d_in[1];
  const int*  tgt  = (const int*)d_in[2];
  const void* emb  = d_in[3];
  const void* Wih  = d_in[4];
  const void* Whh  = d_in[5];
  const void* bih  = d_in[6];
  const void* bhh  = d_in[7];
  const void* Wout = d_in[8];
  const void* bout = d_in[9];

  // workspace carve: ~10.4 MiB, all offsets 256B-aligned
  char* ws = (char*)d_ws;
  int*    flagp  = (int*)(ws + 0);              //       256 B
  float*  gi     = (float*)(ws + 256);          //   786,432 B: [128][1536] f32
  float*  hf     = (float*)(ws + 786688);       // 4,194,304 B: h f32
  __bf16* hb0    = (__bf16*)(ws + 4980992);     // 2,097,152 B: h bf16 ping
  __bf16* hb1    = (__bf16*)(ws + 7078144);     // 2,097,152 B: h bf16 pong
  __bf16* Whh_b  = (__bf16*)(ws + 9175296);     // 1,572,864 B
  __bf16* Wout_b = (__bf16*)(ws + 10748160);    //   131,072 B
  float*  bhhn_f = (float*)(ws + 10879232);     //     2,048 B
  float*  bout_f = (float*)(ws + 10881280);     //       512 B

  probe_dtype<<<1, 256, 0, stream>>>((const unsigned short*)ehid, flagp);
  conv_w<<<3072, 256, 0, stream>>>(Whh, Wout, bhh, bout, flagp,
                                   Whh_b, Wout_b, bhhn_f, bout_f);
  prep_gi<<<768, 256, 0, stream>>>(emb, Wih, bih, bhh, flagp, gi);
  prep_h0<<<4096, 256, 0, stream>>>(ehid, flagp, hf, hb0);

  for (int t = 0; t <= TT; ++t) {
    const __bf16* hbs = (t & 1) ? hb1 : hb0;   // h(t-1)
    __bf16*       hbd = (t & 1) ? hb0 : hb1;   // h(t)
    gru_step<<<640, 256, 0, stream>>>(Whh_b, Wout_b, bhhn_f, bout_f, gi, tgt,
                                      flagp, hbs, hbd, hf, d_out, t);
  }
}

// Round 10
// 2859.621 us; speedup vs baseline: 1.1363x; 1.1363x over previous
//
#include <hip/hip_runtime.h>
#include <hip/hip_bf16.h>

typedef __bf16 bf16x8 __attribute__((ext_vector_type(8)));
typedef float  f32x4  __attribute__((ext_vector_type(4)));

#define MFMA_BF16(a, b, c) __builtin_amdgcn_mfma_f32_16x16x32_bf16((a), (b), (c), 0, 0, 0)

constexpr int TT = 160, BB = 2048, HH = 512, EE = 64, VV = 128, G3 = 1536;
constexpr size_t LPROB_ELEMS = (size_t)TT * BB * VV;  // 41,943,040

// phase-1 LDS: Whh tile [3 gates][16 rows][1024B + 16B pad]
constexpr int BSTRIDE = 1040;               // 1024 + 16 pad -> 2-way banks (free)
constexpr int GSZ = 16 * BSTRIDE;           // 16,640 B per gate
constexpr int SMEM_BYTES = 3 * GSZ;         // 49,920 B

__device__ __forceinline__ float fsigmoid(float x) {
  return 1.0f / (1.0f + __expf(-x));
}
__device__ __forceinline__ float ftanh(float x) {
  float ax = fabsf(x);
  float e = __expf(-2.0f * ax);
  float r = (1.0f - e) / (1.0f + e);
  return x < 0.0f ? -r : r;
}
// dual-dtype scalar load: isbf ? bf16[i] : f32[i]
__device__ __forceinline__ float ld(const void* p, long i, int isbf) {
  return isbf ? (float)((const __bf16*)p)[i] : ((const float*)p)[i];
}

// ---------------- dtype probe ----------------
__global__ __launch_bounds__(256) void probe_dtype(
    const unsigned short* __restrict__ eh, int* __restrict__ flagp) {
  __shared__ int sb[256];
  int tid = threadIdx.x;
  int cnt = 0;
  for (int i = tid; i < 4096; i += 256) {
    unsigned short u = eh[i];
    int e = (u >> 7) & 0xFF;
    if ((u & 0x7FFF) == 0 || (e >= 90 && e <= 150)) cnt++;
  }
  sb[tid] = cnt;
  __syncthreads();
  for (int s = 128; s > 0; s >>= 1) {
    if (tid < s) sb[tid] += sb[tid + s];
    __syncthreads();
  }
  if (tid == 0) *flagp = (sb[0] > 3072) ? 1 : 0;
}

// ---------------- prep kernels ----------------
__global__ __launch_bounds__(256) void conv_w(
    const void* __restrict__ Whh, const void* __restrict__ Wout,
    const void* __restrict__ bhh, const void* __restrict__ bout,
    const int* __restrict__ flagp,
    __bf16* __restrict__ Whh_b, __bf16* __restrict__ Wout_b,
    float* __restrict__ bhhn_f, float* __restrict__ bout_f) {
  const int isbf = *flagp;
  int idx = blockIdx.x * 256 + threadIdx.x;   // 3072 blocks -> 786,432 = 1536*512
  Whh_b[idx] = (__bf16)ld(Whh, idx, isbf);
  if (idx < VV * HH) Wout_b[idx] = (__bf16)ld(Wout, idx, isbf);
  if (idx < HH) bhhn_f[idx] = ld(bhh, 2 * HH + idx, isbf);
  if (idx < VV) bout_f[idx] = ld(bout, idx, isbf);
}

// gi_vocab[v][n] = relu(emb[v]) . W_ih[n] + b_ih[n] + (n < 1024 ? b_hh[n] : 0)
__global__ __launch_bounds__(256) void prep_gi(
    const void* __restrict__ emb, const void* __restrict__ Wih,
    const void* __restrict__ bih, const void* __restrict__ bhh,
    const int* __restrict__ flagp, float* __restrict__ gi) {
  const int isbf = *flagp;
  int idx = blockIdx.x * 256 + threadIdx.x;   // 768 blocks -> exactly 128*1536
  int v = idx / G3;
  int n = idx - v * G3;
  float s = 0.0f;
#pragma unroll 8
  for (int k = 0; k < EE; ++k) {
    float x = ld(emb, v * EE + k, isbf);
    x = x > 0.0f ? x : 0.0f;
    s += x * ld(Wih, (long)n * EE + k, isbf);
  }
  s += ld(bih, n, isbf);
  if (n < 2 * HH) s += ld(bhh, n, isbf);
  gi[idx] = s;
}

// h0 = encoder_hidden[0]: fp32 state + bf16 mirror for MFMA
__global__ __launch_bounds__(256) void prep_h0(
    const void* __restrict__ ehid, const int* __restrict__ flagp,
    float* __restrict__ hf, __bf16* __restrict__ hb0) {
  const int isbf = *flagp;
  int idx = blockIdx.x * 256 + threadIdx.x;   // 4096 blocks -> 1,048,576
  float v = ld(ehid, idx, isbf);
  hf[idx] = v;
  hb0[idx] = (__bf16)v;
}

// ---------------- per-step kernel ----------------
// Grid 576 x 256, launched 162 times (t = 0..161).
// Blocks [0,512): phase 1 — grp=bid&15 owns h rows grp*128..+128; colTile=bid>>4
//   owns GRU output cols colTile*16..+16 of all 3 gates. Whh tile (49KB)
//   LDS-staged; epilogue inputs prefetched.
//   FUSED LOGITS: blocks with colTile>=24 (t>=1) also compute raw logits of
//   h(t-1) for their wave's OWN 32 A-rows x Wout tile vt=colTile-24 — the
//   A-frags are already loaded for the GRU, B is 16 direct loads/wave hidden
//   under the staged-B MFMAs (+2 MFMA/k0 on a 2%-utilized pipe). Raw
//   logits+bias -> llog ping-pong (f32). t==160: hf bulk copy + logits-only
//   for h(159). t==161: return.
// Blocks [512,576): softmax pass — at launch t, log_softmax of llog[s=t-2]
//   (written by P1 in the PREVIOUS launch; kernel boundary = sync), 32 rows
//   per block, shfl-only, writes final output.
// Pipeline safety: P1 writes llog[(t-1)&1], softmax reads llog[(t-2)&1] —
// opposite parities, no race; s=0 written at t=1, first read at t=2.
__global__ __launch_bounds__(256, 3) void gru_step(
    const __bf16* __restrict__ Whh, const __bf16* __restrict__ Wout,
    const float* __restrict__ bhhn_f, const float* __restrict__ bout_f,
    const float* __restrict__ gi, const int* __restrict__ tgt,
    const int* __restrict__ flagp,
    const __bf16* __restrict__ hbs,   // h(t-1) bf16
    __bf16* __restrict__ hbd,         // h(t) bf16 (written)
    float* __restrict__ hf,           // h f32, single buffer (own-element RMW)
    float* __restrict__ llog0, float* __restrict__ llog1,
    void* __restrict__ outp, int t) {
  __shared__ __align__(16) char smem[SMEM_BYTES];

  const int tid = threadIdx.x;
  const int bid = blockIdx.x;
  const int w = tid >> 6;
  const int lane = tid & 63;
  const int q = lane >> 4;
  const int l16 = lane & 15;
  const int isbf = *flagp;
  const f32x4 fzero = {0.0f, 0.0f, 0.0f, 0.0f};

  if (bid < 512) {
    if (t == 161) return;
    const int grp = bid & 15;
    const int colTile = bid >> 4;
    const int mBase = grp * 128 + w * 32;
    const bool doLog = (colTile >= 24) && (t >= 1);
    const int vt = colTile - 24;
    float* lw = ((t - 1) & 1) ? llog1 : llog0;   // llog[s&1], s = t-1
    const __bf16* aRow0 = hbs + (size_t)(mBase + l16) * HH + q * 8;
    const __bf16* aRow1 = aRow0 + 16 * HH;

    if (t == 160) {
      // final hidden: outp[LPROB + idx] = hf[idx] in output dtype
      int base = bid * 2048 + tid * 8;
      const float* src = hf + base;
      if (isbf) {
        bf16x8 v;
#pragma unroll
        for (int i = 0; i < 8; ++i) v[i] = (__bf16)src[i];
        *(bf16x8*)((__bf16*)outp + LPROB_ELEMS + base) = v;
      } else {
        f32x4 v0 = *(const f32x4*)src;
        f32x4 v1 = *(const f32x4*)(src + 4);
        float* dst = (float*)outp + LPROB_ELEMS + base;
        *(f32x4*)dst = v0;
        *(f32x4*)(dst + 4) = v1;
      }
      if (doLog) {
        // logits-only of h(159) (hbs == hb0 == H_159 at t==160)
        const __bf16* bpo = Wout + (size_t)(vt * 16 + l16) * HH + q * 8;
        f32x4 acc2[2];
        acc2[0] = fzero; acc2[1] = fzero;
#pragma unroll
        for (int k0 = 0; k0 < HH; k0 += 32) {
          bf16x8 a0 = *(const bf16x8*)(aRow0 + k0);
          bf16x8 a1 = *(const bf16x8*)(aRow1 + k0);
          bf16x8 b  = *(const bf16x8*)(bpo + k0);
          acc2[0] = MFMA_BF16(a0, b, acc2[0]);
          acc2[1] = MFMA_BF16(a1, b, acc2[1]);
        }
        const float bo = bout_f[vt * 16 + l16];
#pragma unroll
        for (int ms = 0; ms < 2; ++ms)
#pragma unroll
          for (int rg = 0; rg < 4; ++rg)
            lw[(size_t)(mBase + ms * 16 + q * 4 + rg) * VV + vt * 16 + l16] =
                acc2[ms][rg] + bo;
      }
      return;
    }

    const int c = colTile * 16 + l16;
    const float bhhn = bhhn_f[c];

    // ---- stage B tile: Whh rows {g*512 + colTile*16 .. +16}, 49KB burst ----
    {
      const char* src0 = (const char*)(Whh + (size_t)(colTile * 16) * HH);
#pragma unroll
      for (int g = 0; g < 3; ++g) {
        const char* sg = src0 + (size_t)g * (HH * HH * 2);
#pragma unroll
        for (int j = 0; j < 4; ++j) {
          int off = (tid + j * 256) * 16;        // 0..16368
          bf16x8 v = *(const bf16x8*)(sg + off);
          *(bf16x8*)(smem + g * GSZ + (off >> 10) * BSTRIDE + (off & 1023)) = v;
        }
      }
    }

    // ---- prefetch epilogue inputs (independent of K-loop) ----
    int tk[2][4];
    float hold[2][4];
#pragma unroll
    for (int ms = 0; ms < 2; ++ms)
#pragma unroll
      for (int rg = 0; rg < 4; ++rg) {
        int row = mBase + ms * 16 + q * 4 + rg;
        tk[ms][rg] = (t == 0) ? 0 : tgt[row * TT + (t - 1)];
        hold[ms][rg] = hf[(size_t)row * HH + c];
      }
    float gv[2][4][3];
#pragma unroll
    for (int ms = 0; ms < 2; ++ms)
#pragma unroll
      for (int rg = 0; rg < 4; ++rg) {
        const float* gvp = gi + (size_t)tk[ms][rg] * G3 + c;
        gv[ms][rg][0] = gvp[0];
        gv[ms][rg][1] = gvp[HH];
        gv[ms][rg][2] = gvp[2 * HH];
      }
    __syncthreads();   // B tile staged

    // ---- gh = h(t-1) @ W_hh^T (A global, B LDS) + fused logits MFMAs ----
    f32x4 acc[2][3];
#pragma unroll
    for (int ms = 0; ms < 2; ++ms)
#pragma unroll
      for (int gg = 0; gg < 3; ++gg) acc[ms][gg] = fzero;
    f32x4 acc2[2];
    acc2[0] = fzero; acc2[1] = fzero;

    const char* bb = smem + l16 * BSTRIDE + q * 16;
    const __bf16* bpo = Wout + (size_t)(vt * 16 + l16) * HH + q * 8;

#pragma unroll 8
    for (int k0 = 0; k0 < HH; k0 += 32) {
      bf16x8 a0 = *(const bf16x8*)(aRow0 + k0);
      bf16x8 a1 = *(const bf16x8*)(aRow1 + k0);
#pragma unroll
      for (int gg = 0; gg < 3; ++gg) {
        bf16x8 bf = *(const bf16x8*)(bb + gg * GSZ + k0 * 2);
        acc[0][gg] = MFMA_BF16(a0, bf, acc[0][gg]);
        acc[1][gg] = MFMA_BF16(a1, bf, acc[1][gg]);
      }
      if (doLog) {
        bf16x8 b = *(const bf16x8*)(bpo + k0);
        acc2[0] = MFMA_BF16(a0, b, acc2[0]);
        acc2[1] = MFMA_BF16(a1, b, acc2[1]);
      }
    }

    // ---- GRU epilogue: everything already in registers ----
#pragma unroll
    for (int ms = 0; ms < 2; ++ms) {
#pragma unroll
      for (int rg = 0; rg < 4; ++rg) {
        int row = mBase + ms * 16 + q * 4 + rg;
        float r_ = fsigmoid(acc[ms][0][rg] + gv[ms][rg][0]);
        float z_ = fsigmoid(acc[ms][1][rg] + gv[ms][rg][1]);
        float n_ = ftanh(gv[ms][rg][2] + r_ * (acc[ms][2][rg] + bhhn));
        size_t hi = (size_t)row * HH + c;
        float hv = (1.0f - z_) * n_ + z_ * hold[ms][rg];
        hf[hi] = hv;
        hbd[hi] = (__bf16)hv;
      }
    }

    // ---- store raw logits tile (rows = wave's own 32, cols vt*16..+16) ----
    if (doLog) {
      const float bo = bout_f[vt * 16 + l16];
#pragma unroll
      for (int ms = 0; ms < 2; ++ms)
#pragma unroll
        for (int rg = 0; rg < 4; ++rg)
          lw[(size_t)(mBase + ms * 16 + q * 4 + rg) * VV + vt * 16 + l16] =
              acc2[ms][rg] + bo;
    }
  } else {
    // ---- softmax pass: finish llog[s = t-2] (written last launch) ----
    if (t < 2) return;
    const int s = t - 2;
    const float* lr = (s & 1) ? llog1 : llog0;
    const int row = (bid - 512) * 32 + (tid >> 3);
    const int seg = tid & 7;
    const float* src = lr + (size_t)row * VV + seg * 16;
    float x[16];
    float m = -3.0e38f;
#pragma unroll
    for (int i = 0; i < 16; ++i) { x[i] = src[i]; m = fmaxf(m, x[i]); }
#pragma unroll
    for (int d = 1; d < 8; d <<= 1) m = fmaxf(m, __shfl_xor(m, d, 8));
    float ssum = 0.0f;
#pragma unroll
    for (int i = 0; i < 16; ++i) ssum += __expf(x[i] - m);
#pragma unroll
    for (int d = 1; d < 8; d <<= 1) ssum += __shfl_xor(ssum, d, 8);
    float lg = m + __logf(ssum);
    size_t ofs = (size_t)s * (BB * VV) + (size_t)row * VV + seg * 16;
    if (isbf) {
      bf16x8 o0, o1;
#pragma unroll
      for (int i = 0; i < 8; ++i) { o0[i] = (__bf16)(x[i] - lg); o1[i] = (__bf16)(x[8 + i] - lg); }
      *(bf16x8*)((__bf16*)outp + ofs) = o0;
      *(bf16x8*)((__bf16*)outp + ofs + 8) = o1;
    } else {
      float* dst = (float*)outp + ofs;
#pragma unroll
      for (int i = 0; i < 16; i += 4) {
        f32x4 o;
#pragma unroll
        for (int j = 0; j < 4; ++j) o[j] = x[i + j] - lg;
        *(f32x4*)(dst + i) = o;
      }
    }
  }
}

// ---------------- launcher ----------------
extern "C" void kernel_launch(void* const* d_in, const int* in_sizes, int n_in,
                              void* d_out, int out_size, void* d_ws, size_t ws_size,
                              hipStream_t stream) {
  // setup_inputs order:
  // 0 encoder_outputs (unused), 1 encoder_hidden, 2 target_tensor, 3 embedding,
  // 4 W_ih, 5 W_hh, 6 b_ih, 7 b_hh, 8 W_out, 9 b_out
  const void* ehid = d_in[1];
  const int*  tgt  = (const int*)d_in[2];
  const void* emb  = d_in[3];
  const void* Wih  = d_in[4];
  const void* Whh  = d_in[5];
  const void* bih  = d_in[6];
  const void* bhh  = d_in[7];
  const void* Wout = d_in[8];
  const void* bout = d_in[9];

  // workspace carve: ~12.4 MiB, all offsets 256B-aligned
  char* ws = (char*)d_ws;
  int*    flagp  = (int*)(ws + 0);              //       256 B
  float*  gi     = (float*)(ws + 256);          //   786,432 B: [128][1536] f32
  float*  hf     = (float*)(ws + 786688);       // 4,194,304 B: h f32
  __bf16* hb0    = (__bf16*)(ws + 4980992);     // 2,097,152 B: h bf16 ping
  __bf16* hb1    = (__bf16*)(ws + 7078144);     // 2,097,152 B: h bf16 pong
  __bf16* Whh_b  = (__bf16*)(ws + 9175296);     // 1,572,864 B
  __bf16* Wout_b = (__bf16*)(ws + 10748160);    //   131,072 B
  float*  bhhn_f = (float*)(ws + 10879232);     //     2,048 B
  float*  bout_f = (float*)(ws + 10881280);     //       512 B
  float*  llog0  = (float*)(ws + 10881792);     // 1,048,576 B: raw logits ping
  float*  llog1  = (float*)(ws + 11930368);     // 1,048,576 B: raw logits pong

  probe_dtype<<<1, 256, 0, stream>>>((const unsigned short*)ehid, flagp);
  conv_w<<<3072, 256, 0, stream>>>(Whh, Wout, bhh, bout, flagp,
                                   Whh_b, Wout_b, bhhn_f, bout_f);
  prep_gi<<<768, 256, 0, stream>>>(emb, Wih, bih, bhh, flagp, gi);
  prep_h0<<<4096, 256, 0, stream>>>(ehid, flagp, hf, hb0);

  for (int t = 0; t <= 161; ++t) {
    const __bf16* hbs = (t & 1) ? hb1 : hb0;   // h(t-1)
    __bf16*       hbd = (t & 1) ? hb0 : hb1;   // h(t)
    gru_step<<<576, 256, 0, stream>>>(Whh_b, Wout_b, bhhn_f, bout_f, gi, tgt,
                                      flagp, hbs, hbd, hf, llog0, llog1,
                                      d_out, t);
  }
}